// Round 2
// baseline (321.596 us; speedup 1.0000x reference)
//
#include <hip/hip_runtime.h>

#define CIN 8
#define FN 4
#define HSZ 256
#define NB 8

#define PV1F 16777216.0f            /* floor(2^31/128) = 2^24 exactly */
#define INV_PV1 5.9604644775390625e-08f  /* 2^-24, exact */
#define PV2F 671088.0f              /* floor(2^31/(5*5*128)) = floor(2^31/3200) */

__device__ __forceinline__ float tanh_fast(float x) {
    // tanh(x) = 1 - 2/(exp(2x)+1); exp(2x) = exp2(x * 2*log2(e))
    float e = __builtin_amdgcn_exp2f(x * 2.885390081777927f);
    return 1.0f - 2.0f * __builtin_amdgcn_rcpf(e + 1.0f);
}

// ---------------- kernel 1: totalistic kernel preprocessing ----------------
// ktot[f][c][i][j] = 0.125*(sym(k)+sym(k^T))[i][j] - mean
__global__ void k_totalistic(const float* __restrict__ kern, float* __restrict__ ktot) {
    int fc = blockIdx.x;                 // 0..31  (= f*CIN + c)
    const float* kk = kern + fc * 25;
    __shared__ float zsh[25];
    int t = threadIdx.x;
    if (t < 25) {
        int i = t / 5, j = t % 5;
        float v = kk[i*5 + j] + kk[(4-i)*5 + j] + kk[i*5 + (4-j)] + kk[(4-i)*5 + (4-j)]
                + kk[j*5 + i] + kk[j*5 + (4-i)] + kk[(4-j)*5 + i] + kk[(4-j)*5 + (4-i)];
        zsh[t] = 0.125f * v;
    }
    __syncthreads();
    if (t < 25) {
        float m = 0.0f;
        #pragma unroll
        for (int q = 0; q < 25; q++) m += zsh[q];
        m *= (1.0f / 25.0f);
        ktot[fc * 25 + t] = zsh[t] - m;
    }
}

// ---------------- kernel 2: conv + MLP + second-min + residual ----------------
__global__ __launch_bounds__(256) void k_main(
    const float* __restrict__ x, const float* __restrict__ ktot,
    const float* __restrict__ biases, const float* __restrict__ W1,
    const float* __restrict__ W2, const float* __restrict__ W3,
    const float* __restrict__ W4, const unsigned* __restrict__ urate,
    float* __restrict__ out)
{
    int blk = blockIdx.x;
    int b = blk >> 8;
    int h = blk & 255;
    int w = threadIdx.x;

    int col[5], row[5];
    #pragma unroll
    for (int d = 0; d < 5; d++) {
        col[d] = (w + d + 254) & 255;
        row[d] = (h + d + 254) & 255;
    }

    // ---- conv over all 4 filters ----
    float acc0 = 0.f, acc1 = 0.f, acc2 = 0.f, acc3 = 0.f;
    for (int c = 0; c < CIN; c++) {
        const float* xb = x + (((size_t)b * CIN + c) << 16);
        const float* kt = ktot + c * 25;           // f stride = CIN*25 = 200
        #pragma unroll
        for (int di = 0; di < 5; di++) {
            const float* rp = xb + (row[di] << 8);
            #pragma unroll
            for (int dj = 0; dj < 5; dj++) {
                float zv = floorf(rp[col[dj]] * PV2F);
                int tap = di * 5 + dj;
                acc0 += zv * kt[0 * 200 + tap];
                acc1 += zv * kt[1 * 200 + tap];
                acc2 += zv * kt[2 * 200 + tap];
                acc3 += zv * kt[3 * 200 + tap];
            }
        }
    }

    // ---- per-f MLP; maintain two smallest per output channel ----
    float m0[8], m1[8];
    #pragma unroll
    for (int o = 0; o < 8; o++) { m0[o] = 1e30f; m1[o] = 1e30f; }

    for (int f = 0; f < FN; f++) {
        float accf = (f == 0) ? acc0 : (f == 1) ? acc1 : (f == 2) ? acc2 : acc3;
        float p  = floorf(accf + biases[f]) / PV2F;
        float t0 = floorf(p * PV1F);               // exact: *2^24

        const float* w1 = W1 + f * 32;
        const float* w2 = W2 + f * 1024;
        const float* w3 = W3 + f * 1024;
        const float* w4 = W4 + f * 256;

        float a[32], t[32];

        // layer 1: c-dim == 1
        #pragma unroll
        for (int o = 0; o < 32; o++)
            a[o] = tanh_fast(floorf(w1[o] * t0) * INV_PV1);

        // layer 2
        #pragma unroll
        for (int c = 0; c < 32; c++) t[c] = floorf(a[c] * PV1F);
        #pragma unroll
        for (int o = 0; o < 32; o++) {
            float s = 0.f;
            #pragma unroll
            for (int c = 0; c < 32; c++) s += w2[o * 32 + c] * t[c];
            a[o] = tanh_fast(floorf(s) * INV_PV1);
        }

        // layer 3
        #pragma unroll
        for (int c = 0; c < 32; c++) t[c] = floorf(a[c] * PV1F);
        #pragma unroll
        for (int o = 0; o < 32; o++) {
            float s = 0.f;
            #pragma unroll
            for (int c = 0; c < 32; c++) s += w3[o * 32 + c] * t[c];
            a[o] = tanh_fast(floorf(s) * INV_PV1);
        }

        // layer 4 -> 8 outputs; update running two-smallest
        #pragma unroll
        for (int c = 0; c < 32; c++) t[c] = floorf(a[c] * PV1F);
        #pragma unroll
        for (int o = 0; o < 8; o++) {
            float s = 0.f;
            #pragma unroll
            for (int c = 0; c < 32; c++) s += w4[o * 32 + c] * t[c];
            float v = tanh_fast(floorf(s) * INV_PV1);
            float nm0 = fminf(m0[o], v);
            float nm1 = fminf(m1[o], fmaxf(m0[o], v));
            m0[o] = nm0; m1[o] = nm1;
        }
    }

    // update_rate: robust to int32 or float32 encoding (value is 1)
    unsigned ub = urate[0];
    float ur = (ub < 0x38000000u) ? (float)(int)ub : __uint_as_float(ub);

    #pragma unroll
    for (int o = 0; o < 8; o++) {
        int oidx = ((b * CIN + o) << 16) + (h << 8) + w;
        float xv = x[oidx];
        float v = xv + m1[o] * ur;                 // m1 = second smallest over f
        out[oidx] = fminf(fmaxf(v, 0.0f), 1.0f);
    }
}

extern "C" void kernel_launch(void* const* d_in, const int* in_sizes, int n_in,
                              void* d_out, int out_size, void* d_ws, size_t ws_size,
                              hipStream_t stream) {
    const float* x       = (const float*)d_in[0];
    const float* kernels = (const float*)d_in[1];
    const float* biases  = (const float*)d_in[2];
    const float* W1      = (const float*)d_in[3];
    const float* W2      = (const float*)d_in[4];
    const float* W3      = (const float*)d_in[5];
    const float* W4      = (const float*)d_in[6];
    const unsigned* ur   = (const unsigned*)d_in[7];
    float* out = (float*)d_out;
    float* ktot = (float*)d_ws;                    // 4*8*25 = 800 floats

    k_totalistic<<<FN * CIN, 64, 0, stream>>>(kernels, ktot);
    k_main<<<NB * HSZ, 256, 0, stream>>>(x, ktot, biases, W1, W2, W3, W4, ur, out);
}

// Round 3
// 280.505 us; speedup vs baseline: 1.1465x; 1.1465x over previous
//
#include <hip/hip_runtime.h>

#define CIN 8
#define FN 4
#define HSZ 256
#define NB 8

#define PV1F 16777216.0f                  /* floor(2^31/128) = 2^24 exactly */
#define INV_PV1 5.9604644775390625e-08f   /* 2^-24, exact */
#define PV2F 671088.0f                    /* floor(2^31/3200) */

__device__ __forceinline__ float tanh_fast(float x) {
    // tanh(x) = 1 - 2/(exp(2x)+1); exp(2x) = exp2(x * 2*log2(e))
    float e = __builtin_amdgcn_exp2f(x * 2.885390081777927f);
    return 1.0f - 2.0f * __builtin_amdgcn_rcpf(e + 1.0f);
}

// ---------------- kernel 1: totalistic kernel preprocessing ----------------
__global__ void k_totalistic(const float* __restrict__ kern, float* __restrict__ ktot) {
    int fc = blockIdx.x;                 // 0..31  (= f*CIN + c)
    const float* kk = kern + fc * 25;
    __shared__ float zsh[25];
    int t = threadIdx.x;
    if (t < 25) {
        int i = t / 5, j = t % 5;
        float v = kk[i*5 + j] + kk[(4-i)*5 + j] + kk[i*5 + (4-j)] + kk[(4-i)*5 + (4-j)]
                + kk[j*5 + i] + kk[j*5 + (4-i)] + kk[(4-j)*5 + i] + kk[(4-j)*5 + (4-i)];
        zsh[t] = 0.125f * v;
    }
    __syncthreads();
    if (t < 25) {
        float m = 0.0f;
        #pragma unroll
        for (int q = 0; q < 25; q++) m += zsh[q];
        m *= (1.0f / 25.0f);
        ktot[fc * 25 + t] = zsh[t] - m;
    }
}

// ---------------- kernel 2: one wave per filter, 64 pixels per block ----------------
// block = 256 thr = 4 waves; wave f computes filter f for pixels (b,h,w0+lane)
__global__ __launch_bounds__(256, 4) void k_main(
    const float* __restrict__ x, const float* __restrict__ ktot,
    const float* __restrict__ biases, const float* __restrict__ W1,
    const float* __restrict__ W2, const float* __restrict__ W3,
    const float* __restrict__ W4, const unsigned* __restrict__ urate,
    float* __restrict__ out)
{
    int tid = threadIdx.x;
    int lane = tid & 63;
    int f = __builtin_amdgcn_readfirstlane(tid >> 6);   // wave-uniform -> SGPR

    int blk = blockIdx.x;            // 8192 = b(8) * h(256) * seg(4)
    int seg = blk & 3;
    int h   = (blk >> 2) & 255;
    int b   = blk >> 10;
    int w0  = seg << 6;

    __shared__ float zt[CIN][5][68];      // quantized halo tile, 10.9 KB
    __shared__ float red[8][FN][64];      // [out_ch][f][pixel], 8 KB

    // ---- stage z = floor(x*PV2) for rows h-2..h+2, cols w0-2..w0+65 (wrapped) ----
    for (int e = tid; e < CIN * 5 * 68; e += 256) {
        int c  = e / (5 * 68);
        int r  = e % (5 * 68);
        int di = r / 68;
        int dj = r % 68;
        int hh = (h + di + 254) & 255;
        int ww = (w0 + dj + 254) & 255;
        float xv = x[((b * CIN + c) << 16) + (hh << 8) + ww];
        zt[c][di][dj] = floorf(xv * PV2F);
    }
    __syncthreads();

    // ---- conv for this thread's (pixel=lane, filter=f) ----
    const float* kt = ktot + f * 200;     // [c][5][5]
    float acc = 0.f;
    #pragma unroll
    for (int c = 0; c < CIN; c++) {
        #pragma unroll
        for (int di = 0; di < 5; di++) {
            #pragma unroll
            for (int dj = 0; dj < 5; dj++)
                acc += zt[c][di][lane + dj] * kt[c * 25 + di * 5 + dj];
        }
    }

    // ---- MLP for filter f ----
    float p  = floorf(acc + biases[f]) / PV2F;
    float t0 = floorf(p * PV1F);          // exact *2^24

    const float* w1 = W1 + f * 32;
    const float* w2 = W2 + f * 1024;
    const float* w3 = W3 + f * 1024;
    const float* w4 = W4 + f * 256;

    float a[32], an[32];

    // layer 1 (c-dim == 1)
    #pragma unroll
    for (int o = 0; o < 32; o++)
        a[o] = tanh_fast(floorf(w1[o] * t0) * INV_PV1);

    // layer 2
    #pragma unroll
    for (int c = 0; c < 32; c++) a[c] = floorf(a[c] * PV1F);
    #pragma unroll
    for (int o = 0; o < 32; o++) {
        float s = 0.f;
        #pragma unroll
        for (int c = 0; c < 32; c++) s += w2[o * 32 + c] * a[c];
        an[o] = tanh_fast(floorf(s) * INV_PV1);
    }

    // layer 3
    #pragma unroll
    for (int c = 0; c < 32; c++) an[c] = floorf(an[c] * PV1F);
    #pragma unroll
    for (int o = 0; o < 32; o++) {
        float s = 0.f;
        #pragma unroll
        for (int c = 0; c < 32; c++) s += w3[o * 32 + c] * an[c];
        a[o] = tanh_fast(floorf(s) * INV_PV1);
    }

    // layer 4 -> 8 outputs, stash to LDS for cross-wave reduction
    #pragma unroll
    for (int c = 0; c < 32; c++) a[c] = floorf(a[c] * PV1F);
    #pragma unroll
    for (int o = 0; o < 8; o++) {
        float s = 0.f;
        #pragma unroll
        for (int c = 0; c < 32; c++) s += w4[o * 32 + c] * a[c];
        red[o][f][lane] = tanh_fast(floorf(s) * INV_PV1);
    }
    __syncthreads();

    // ---- second-smallest across f + residual + clip; 2 (o,pixel) pairs per thread ----
    unsigned ub = urate[0];
    float ur = (ub < 0x38000000u) ? (float)(int)ub : __uint_as_float(ub);

    #pragma unroll
    for (int q = 0; q < 2; q++) {
        int pidx = tid + q * 256;
        int o   = pidx >> 6;
        int pix = pidx & 63;
        float v0 = red[o][0][pix], v1 = red[o][1][pix];
        float v2 = red[o][2][pix], v3 = red[o][3][pix];
        float lo01 = fminf(v0, v1), hi01 = fmaxf(v0, v1);
        float lo23 = fminf(v2, v3), hi23 = fmaxf(v2, v3);
        float second = fminf(fmaxf(lo01, lo23), fminf(hi01, hi23));
        int oidx = ((b * CIN + o) << 16) + (h << 8) + (w0 + pix);
        float xv = x[oidx];
        out[oidx] = fminf(fmaxf(xv + second * ur, 0.0f), 1.0f);
    }
}

extern "C" void kernel_launch(void* const* d_in, const int* in_sizes, int n_in,
                              void* d_out, int out_size, void* d_ws, size_t ws_size,
                              hipStream_t stream) {
    const float* x       = (const float*)d_in[0];
    const float* kernels = (const float*)d_in[1];
    const float* biases  = (const float*)d_in[2];
    const float* W1      = (const float*)d_in[3];
    const float* W2      = (const float*)d_in[4];
    const float* W3      = (const float*)d_in[5];
    const float* W4      = (const float*)d_in[6];
    const unsigned* ur   = (const unsigned*)d_in[7];
    float* out = (float*)d_out;
    float* ktot = (float*)d_ws;                    // 4*8*25 = 800 floats

    k_totalistic<<<FN * CIN, 64, 0, stream>>>(kernels, ktot);
    k_main<<<NB * HSZ * 4, 256, 0, stream>>>(x, ktot, biases, W1, W2, W3, W4, ur, out);
}

// Round 4
// 276.832 us; speedup vs baseline: 1.1617x; 1.0133x over previous
//
#include <hip/hip_runtime.h>

#define CIN 8
#define FN 4
#define HSZ 256
#define NB 8

#define PV1F 16777216.0f                  /* 2^24 exactly */
#define PV2F 671088.0f                    /* floor(2^31/3200) */
#define ACT_C 1.7198652168210516e-07f     /* 2*log2(e)/2^24 */

// returns floor(tanh(floor(s)/2^24) * 2^24)  -- the next layer's input, pre-scaled
__device__ __forceinline__ float act_t(float s) {
    float e = __builtin_amdgcn_exp2f(floorf(s) * ACT_C);
    float r = __builtin_amdgcn_rcpf(e + 1.0f);
    return floorf(fmaf(-33554432.0f, r, 16777216.0f));
}
// final layer: returns tanh(floor(s)/2^24)
__device__ __forceinline__ float act_out(float s) {
    float e = __builtin_amdgcn_exp2f(floorf(s) * ACT_C);
    float r = __builtin_amdgcn_rcpf(e + 1.0f);
    return fmaf(-2.0f, r, 1.0f);
}

// ---------------- kernel 1: totalistic kernel preprocessing ----------------
__global__ void k_totalistic(const float* __restrict__ kern, float* __restrict__ ktot) {
    int fc = blockIdx.x;                 // 0..31  (= f*CIN + c)
    const float* kk = kern + fc * 25;
    __shared__ float zsh[25];
    int t = threadIdx.x;
    if (t < 25) {
        int i = t / 5, j = t % 5;
        float v = kk[i*5 + j] + kk[(4-i)*5 + j] + kk[i*5 + (4-j)] + kk[(4-i)*5 + (4-j)]
                + kk[j*5 + i] + kk[j*5 + (4-i)] + kk[(4-j)*5 + i] + kk[(4-j)*5 + (4-i)];
        zsh[t] = 0.125f * v;
    }
    __syncthreads();
    if (t < 25) {
        float m = 0.0f;
        #pragma unroll
        for (int q = 0; q < 25; q++) m += zsh[q];
        m *= (1.0f / 25.0f);
        ktot[fc * 25 + t] = zsh[t] - m;
    }
}

// ---------------- kernel 2: one wave per filter, 64 pixels per block ----------------
__global__ __launch_bounds__(256, 2) void k_main(
    const float* __restrict__ x, const float* __restrict__ ktot,
    const float* __restrict__ biases, const float* __restrict__ W1,
    const float* __restrict__ W2, const float* __restrict__ W3,
    const float* __restrict__ W4, const unsigned* __restrict__ urate,
    float* __restrict__ out)
{
    int tid = threadIdx.x;
    int lane = tid & 63;
    int f = __builtin_amdgcn_readfirstlane(tid >> 6);   // wave-uniform -> SGPR

    int blk = blockIdx.x;            // 8192 = b(8) * h(256) * seg(4)
    int seg = blk & 3;
    int h   = (blk >> 2) & 255;
    int b   = blk >> 10;
    int w0  = seg << 6;

    __shared__ float zt[CIN][5][68];      // quantized halo tile, 10.9 KB
    __shared__ float red[8][FN][64];      // [out_ch][f][pixel], 8 KB

    // ---- stage z = floor(x*PV2) for rows h-2..h+2, cols w0-2..w0+65 (wrapped) ----
    for (int e = tid; e < CIN * 5 * 68; e += 256) {
        int c  = e / (5 * 68);
        int r  = e % (5 * 68);
        int di = r / 68;
        int dj = r % 68;
        int hh = (h + di + 254) & 255;
        int ww = (w0 + dj + 254) & 255;
        float xv = x[((b * CIN + c) << 16) + (hh << 8) + ww];
        zt[c][di][dj] = floorf(xv * PV2F);
    }
    __syncthreads();

    // ---- conv for (pixel=lane, filter=f); 2 partial accs for ILP ----
    const float* kt = ktot + f * 200;     // [c][5][5]
    float accA = 0.f, accB = 0.f;
    #pragma unroll
    for (int c = 0; c < CIN; c++) {
        #pragma unroll
        for (int di = 0; di < 5; di++) {
            #pragma unroll
            for (int dj = 0; dj < 5; dj++) {
                float v = zt[c][di][lane + dj] * kt[c * 25 + di * 5 + dj];
                if ((di ^ c) & 1) accA += v; else accB += v;
            }
        }
    }
    float acc = accA + accB;

    // ---- MLP for filter f; t-arrays hold floor(h*2^24) directly ----
    float p  = floorf(acc + biases[f]) / PV2F;
    float t0 = floorf(p * PV1F);

    const float* w1 = W1 + f * 32;
    const float* w2 = W2 + f * 1024;
    const float* w3 = W3 + f * 1024;
    const float* w4 = W4 + f * 256;

    float ta[32], tb[32];

    // layer 1 (c-dim == 1)
    #pragma unroll
    for (int o = 0; o < 32; o++)
        ta[o] = act_t(w1[o] * t0);

    // layer 2
    #pragma unroll
    for (int o = 0; o < 32; o++) {
        float s = 0.f;
        #pragma unroll
        for (int c = 0; c < 32; c++) s += w2[o * 32 + c] * ta[c];
        tb[o] = act_t(s);
    }

    // layer 3
    #pragma unroll
    for (int o = 0; o < 32; o++) {
        float s = 0.f;
        #pragma unroll
        for (int c = 0; c < 32; c++) s += w3[o * 32 + c] * tb[c];
        ta[o] = act_t(s);
    }

    // layer 4 -> 8 outputs, stash to LDS for cross-wave reduction
    #pragma unroll
    for (int o = 0; o < 8; o++) {
        float s = 0.f;
        #pragma unroll
        for (int c = 0; c < 32; c++) s += w4[o * 32 + c] * ta[c];
        red[o][f][lane] = act_out(s);
    }
    __syncthreads();

    // ---- second-smallest across f + residual + clip; 2 (o,pixel) pairs/thread ----
    unsigned ub = urate[0];
    float ur = (ub < 0x38000000u) ? (float)(int)ub : __uint_as_float(ub);

    #pragma unroll
    for (int q = 0; q < 2; q++) {
        int pidx = tid + q * 256;
        int o   = pidx >> 6;
        int pix = pidx & 63;
        float v0 = red[o][0][pix], v1 = red[o][1][pix];
        float v2 = red[o][2][pix], v3 = red[o][3][pix];
        float lo01 = fminf(v0, v1), hi01 = fmaxf(v0, v1);
        float lo23 = fminf(v2, v3), hi23 = fmaxf(v2, v3);
        float second = fminf(fmaxf(lo01, lo23), fminf(hi01, hi23));
        int oidx = ((b * CIN + o) << 16) + (h << 8) + (w0 + pix);
        float xv = x[oidx];
        out[oidx] = fminf(fmaxf(xv + second * ur, 0.0f), 1.0f);
    }
}

extern "C" void kernel_launch(void* const* d_in, const int* in_sizes, int n_in,
                              void* d_out, int out_size, void* d_ws, size_t ws_size,
                              hipStream_t stream) {
    const float* x       = (const float*)d_in[0];
    const float* kernels = (const float*)d_in[1];
    const float* biases  = (const float*)d_in[2];
    const float* W1      = (const float*)d_in[3];
    const float* W2      = (const float*)d_in[4];
    const float* W3      = (const float*)d_in[5];
    const float* W4      = (const float*)d_in[6];
    const unsigned* ur   = (const unsigned*)d_in[7];
    float* out = (float*)d_out;
    float* ktot = (float*)d_ws;                    // 4*8*25 = 800 floats

    k_totalistic<<<FN * CIN, 64, 0, stream>>>(kernels, ktot);
    k_main<<<NB * HSZ * 4, 256, 0, stream>>>(x, ktot, biases, W1, W2, W3, W4, ur, out);
}